// Round 1
// baseline (155.608 us; speedup 1.0000x reference)
//
#include <hip/hip_runtime.h>

#define BN 2
#define QN 900
#define CN 256
#define NCAM 6
#define HF 112
#define WF 200
#define ZL 10
#define YL 128
#define XL 128

__global__ __launch_bounds__(256) void mafs_fused(
    const float* __restrict__ query,
    const float* __restrict__ rp,
    const float* __restrict__ imgf,
    const float* __restrict__ lidf,
    const float* __restrict__ l2i,
    const float* __restrict__ cam_w, const float* __restrict__ cam_b,
    const float* __restrict__ lid_w, const float* __restrict__ lid_b,
    const float* __restrict__ att_w1, const float* __restrict__ att_b1,
    const float* __restrict__ att_w2, const float* __restrict__ att_b2,
    const float* __restrict__ fus_w1, const float* __restrict__ fus_b1,
    const float* __restrict__ ln_g, const float* __restrict__ ln_b,
    const float* __restrict__ fus_w2, const float* __restrict__ fus_b2,
    float* __restrict__ out)
{
  const int bq = blockIdx.x;           // 0..1799
  const int b  = bq / QN;
  const int tid = threadIdx.x;         // 0..255 == channel

  __shared__ float s_q[CN], s_fc[CN], s_fl[CN], s_pc[CN], s_pl[CN], s_t[CN];
  __shared__ float s_h[64];
  __shared__ float s_red[8];
  __shared__ float s_w[2];

  // query row -> LDS (coalesced)
  s_q[tid] = query[(size_t)bq * CN + tid];

  const float rx = rp[bq*3+0], ry = rp[bq*3+1], rz = rp[bq*3+2];

  // ---------------- camera branch ----------------
  const float ax = rx * 102.4f - 51.2f;
  const float ay = ry * 102.4f - 51.2f;
  const float az = rz * 8.0f   - 5.0f;

  float acc = 0.f, cnt = 0.f;
  #pragma unroll
  for (int n = 0; n < NCAM; ++n) {
    const float* M = l2i + (b*NCAM + n)*16;
    const float c0 = M[0]*ax + M[1]*ay + M[2] *az + M[3];
    const float c1 = M[4]*ax + M[5]*ay + M[6] *az + M[7];
    const float c2 = M[8]*ax + M[9]*ay + M[10]*az + M[11];
    const float dc = fmaxf(c2, 1e-5f);
    const float u = 2.0f * (c0 / dc) / 1599.0f - 1.0f;   // IEEE div, matches ref
    const float v = 2.0f * (c1 / dc) /  899.0f - 1.0f;
    const bool valid = (u >= -1.f) && (u <= 1.f) && (v >= -1.f) && (v <= 1.f)
                       && (c2 > 1e-5f);
    if (valid) {
      cnt += 1.f;
      const float x = ((u + 1.f) * (float)WF - 1.f) * 0.5f;
      const float y = ((v + 1.f) * (float)HF - 1.f) * 0.5f;
      const float x0f = floorf(x), y0f = floorf(y);
      const int   x0 = (int)x0f,  y0 = (int)y0f;
      const float fx = x - x0f,   fy = y - y0f;
      const float w00 = (1.f-fx)*(1.f-fy);
      const float w10 = fx*(1.f-fy);
      const float w01 = (1.f-fx)*fy;
      const float w11 = fx*fy;
      const float* fb = imgf + ((size_t)((b*NCAM + n)*CN) + tid) * (HF*WF);
      const bool xb0 = (x0   >= 0) && (x0   < WF);
      const bool xb1 = (x0+1 >= 0) && (x0+1 < WF);
      const bool yb0 = (y0   >= 0) && (y0   < HF);
      const bool yb1 = (y0+1 >= 0) && (y0+1 < HF);
      const int i00 = y0*WF + x0;
      float sv = 0.f;
      if (xb0 && yb0) sv += w00 * fb[i00];
      if (xb1 && yb0) sv += w10 * fb[i00 + 1];
      if (xb0 && yb1) sv += w01 * fb[i00 + WF];
      if (xb1 && yb1) sv += w11 * fb[i00 + WF + 1];
      acc += sv;
    }
  }
  s_fc[tid] = acc / fmaxf(cnt, 1.f);

  // ---------------- lidar branch ----------------
  {
    const float gx = 2.f*rx - 1.f, gy = 2.f*ry - 1.f, gz = 2.f*rz - 1.f;
    const float x = ((gx + 1.f) * (float)XL - 1.f) * 0.5f;
    const float y = ((gy + 1.f) * (float)YL - 1.f) * 0.5f;
    const float z = ((gz + 1.f) * (float)ZL - 1.f) * 0.5f;
    const float x0f = floorf(x), y0f = floorf(y), z0f = floorf(z);
    const int x0 = (int)x0f, y0 = (int)y0f, z0 = (int)z0f;
    const float fx = x - x0f, fy = y - y0f, fz = z - z0f;
    const float wx[2] = {1.f-fx, fx}, wy[2] = {1.f-fy, fy}, wz[2] = {1.f-fz, fz};
    const bool xb[2] = { x0 >= 0 && x0 < XL, x0+1 >= 0 && x0+1 < XL };
    const bool yb[2] = { y0 >= 0 && y0 < YL, y0+1 >= 0 && y0+1 < YL };
    const bool zb[2] = { z0 >= 0 && z0 < ZL, z0+1 >= 0 && z0+1 < ZL };
    const float* lb = lidf + ((size_t)(b*CN) + tid) * (ZL*YL*XL);
    float sv = 0.f;
    #pragma unroll
    for (int dz = 0; dz < 2; ++dz)
      #pragma unroll
      for (int dy = 0; dy < 2; ++dy)
        #pragma unroll
        for (int dx = 0; dx < 2; ++dx) {
          if (xb[dx] && yb[dy] && zb[dz]) {
            const int idx = (((z0+dz)*YL) + (y0+dy))*XL + (x0+dx);
            sv += wx[dx]*wy[dy]*wz[dz] * lb[idx];
          }
        }
    s_fl[tid] = sv;
  }
  __syncthreads();

  // ---------------- cam/lidar projections + attention MLP ----------------
  float pc = cam_b[tid], pl = lid_b[tid];
  #pragma unroll 4
  for (int k = 0; k < CN; ++k) {
    pc += s_fc[k] * cam_w[k*CN + tid];
    pl += s_fl[k] * lid_w[k*CN + tid];
  }
  if (tid < 64) {
    float h = att_b1[tid];
    #pragma unroll 4
    for (int k = 0; k < CN; ++k) h += s_q[k] * att_w1[k*64 + tid];
    s_h[tid] = fmaxf(h, 0.f);
  }
  __syncthreads();
  if (tid == 0) {
    float l0 = att_b2[0], l1 = att_b2[1];
    for (int j = 0; j < 64; ++j) {
      l0 += s_h[j] * att_w2[2*j];
      l1 += s_h[j] * att_w2[2*j+1];
    }
    const float m  = fmaxf(l0, l1);
    const float e0 = expf(l0 - m), e1 = expf(l1 - m);
    const float inv = 1.f / (e0 + e1);
    s_w[0] = e0 * inv; s_w[1] = e1 * inv;
  }
  __syncthreads();
  s_pc[tid] = s_w[0] * pc;
  s_pl[tid] = s_w[1] * pl;
  __syncthreads();

  // ---------------- fusion layer 1 (512 -> 256) ----------------
  float t1 = fus_b1[tid];
  #pragma unroll 4
  for (int k = 0; k < CN; ++k) t1 += s_pc[k] * fus_w1[k*CN + tid];
  #pragma unroll 4
  for (int k = 0; k < CN; ++k) t1 += s_pl[k] * fus_w1[(CN+k)*CN + tid];

  // ---------------- layer norm + relu ----------------
  const int lane = tid & 63, wv = tid >> 6;
  float ws = t1;
  #pragma unroll
  for (int o = 32; o > 0; o >>= 1) ws += __shfl_down(ws, o);
  if (lane == 0) s_red[wv] = ws;
  __syncthreads();
  if (tid == 0) s_red[4] = (s_red[0]+s_red[1]+s_red[2]+s_red[3]) * (1.f/256.f);
  __syncthreads();
  const float mu = s_red[4];
  const float d = t1 - mu;
  float ws2 = d * d;
  #pragma unroll
  for (int o = 32; o > 0; o >>= 1) ws2 += __shfl_down(ws2, o);
  if (lane == 0) s_red[wv] = ws2;
  __syncthreads();
  if (tid == 0) s_red[5] = (s_red[0]+s_red[1]+s_red[2]+s_red[3]) * (1.f/256.f);
  __syncthreads();
  const float var = s_red[5];
  const float r = rsqrtf(var + 1e-5f);
  const float t2 = fmaxf(d * r * ln_g[tid] + ln_b[tid], 0.f);
  s_t[tid] = t2;
  __syncthreads();

  // ---------------- output projection (256 -> 256) ----------------
  float o = fus_b2[tid];
  #pragma unroll 4
  for (int k = 0; k < CN; ++k) o += s_t[k] * fus_w2[k*CN + tid];
  out[(size_t)bq * CN + tid] = o;
}

extern "C" void kernel_launch(void* const* d_in, const int* in_sizes, int n_in,
                              void* d_out, int out_size, void* d_ws, size_t ws_size,
                              hipStream_t stream) {
  const float* query   = (const float*)d_in[0];
  const float* rpts    = (const float*)d_in[1];
  const float* imgf    = (const float*)d_in[2];
  const float* lidf    = (const float*)d_in[3];
  const float* l2i     = (const float*)d_in[4];
  const float* cam_w   = (const float*)d_in[5];
  const float* cam_b   = (const float*)d_in[6];
  const float* lid_w   = (const float*)d_in[7];
  const float* lid_b   = (const float*)d_in[8];
  const float* att_w1  = (const float*)d_in[9];
  const float* att_b1  = (const float*)d_in[10];
  const float* att_w2  = (const float*)d_in[11];
  const float* att_b2  = (const float*)d_in[12];
  const float* fus_w1  = (const float*)d_in[13];
  const float* fus_b1  = (const float*)d_in[14];
  const float* ln_g    = (const float*)d_in[15];
  const float* ln_b    = (const float*)d_in[16];
  const float* fus_w2  = (const float*)d_in[17];
  const float* fus_b2  = (const float*)d_in[18];
  float* out = (float*)d_out;

  dim3 grid(BN * QN);
  dim3 block(256);
  mafs_fused<<<grid, block, 0, stream>>>(
      query, rpts, imgf, lidf, l2i,
      cam_w, cam_b, lid_w, lid_b,
      att_w1, att_b1, att_w2, att_b2,
      fus_w1, fus_b1, ln_g, ln_b, fus_w2, fus_b2, out);
}

// Round 2
// 125.205 us; speedup vs baseline: 1.2428x; 1.2428x over previous
//
#include <hip/hip_runtime.h>

#define BN 2
#define QN 900
#define CN 256
#define NCAM 6
#define HF 112
#define WF 200
#define ZL 10
#define YL 128
#define XL 128
#define R 4

__global__ __launch_bounds__(256) void mafs_fused(
    const float* __restrict__ query,
    const float* __restrict__ rp,
    const float* __restrict__ imgf,
    const float* __restrict__ lidf,
    const float* __restrict__ l2i,
    const float* __restrict__ cam_w, const float* __restrict__ cam_b,
    const float* __restrict__ lid_w, const float* __restrict__ lid_b,
    const float* __restrict__ att_w1, const float* __restrict__ att_b1,
    const float* __restrict__ att_w2, const float* __restrict__ att_b2,
    const float* __restrict__ fus_w1, const float* __restrict__ fus_b1,
    const float* __restrict__ ln_g, const float* __restrict__ ln_b,
    const float* __restrict__ fus_w2, const float* __restrict__ fus_b2,
    float* __restrict__ out)
{
  const int blk = blockIdx.x;          // 0..449
  const int q0  = blk * R;             // base row (global bq)
  const int b   = q0 / QN;             // uniform per block (900 % 4 == 0)
  const int tid = threadIdx.x;         // channel
  const int lane = tid & 63, wv = tid >> 6;

  __shared__ float s_q[R*CN];          // [r][k]
  __shared__ float s_a[CN*R];          // [ch][r]: cam feat -> gated cam
  __shared__ float s_b[CN*R];          // [ch][r]: lid feat -> gated lid
  __shared__ float s_t[CN*R];          // [ch][r]: post-LN
  __shared__ float s_w0[R], s_w1[R];
  __shared__ float s_sum[R*4], s_sq[R*4];

  // ---- load 4 query rows (coalesced) ----
  #pragma unroll
  for (int r = 0; r < R; ++r)
    s_q[r*CN + tid] = query[(size_t)(q0+r)*CN + tid];
  __syncthreads();

  // ---- attention gate: wave wv handles row wv ----
  {
    const int c = lane;
    const float* qrow = s_q + wv*CN;
    float h = att_b1[c];
    #pragma unroll 4
    for (int k = 0; k < CN; ++k) h += qrow[k] * att_w1[k*64 + c];
    h = fmaxf(h, 0.f);
    float l0 = h * att_w2[2*c], l1 = h * att_w2[2*c+1];
    #pragma unroll
    for (int o = 32; o > 0; o >>= 1) { l0 += __shfl_down(l0,o); l1 += __shfl_down(l1,o); }
    if (lane == 0) {
      l0 += att_b2[0]; l1 += att_b2[1];
      const float m  = fmaxf(l0, l1);
      const float e0 = expf(l0 - m), e1 = expf(l1 - m);
      const float inv = 1.f / (e0 + e1);
      s_w0[wv] = e0 * inv; s_w1[wv] = e1 * inv;
    }
  }

  // ---- reference point coords for the 4 rows ----
  float ax[R], ay[R], az[R], rxx[R], ryy[R], rzz[R];
  #pragma unroll
  for (int r = 0; r < R; ++r) {
    const int bq = q0 + r;
    const float rx = rp[bq*3+0], ry = rp[bq*3+1], rz = rp[bq*3+2];
    rxx[r] = rx; ryy[r] = ry; rzz[r] = rz;
    ax[r] = rx * 102.4f - 51.2f;
    ay[r] = ry * 102.4f - 51.2f;
    az[r] = rz * 8.0f   - 5.0f;
  }

  // ---- camera gathers (valid is block-uniform) ----
  float fc[R] = {0.f,0.f,0.f,0.f}, cnt[R] = {0.f,0.f,0.f,0.f};
  #pragma unroll
  for (int n = 0; n < NCAM; ++n) {
    const float* M = l2i + (size_t)(b*NCAM + n)*16;
    const float m0=M[0],m1=M[1],m2=M[2],m3=M[3];
    const float m4=M[4],m5=M[5],m6=M[6],m7=M[7];
    const float m8=M[8],m9=M[9],m10=M[10],m11=M[11];
    #pragma unroll
    for (int r = 0; r < R; ++r) {
      const float c0 = m0*ax[r] + m1*ay[r] + m2 *az[r] + m3;
      const float c1 = m4*ax[r] + m5*ay[r] + m6 *az[r] + m7;
      const float c2 = m8*ax[r] + m9*ay[r] + m10*az[r] + m11;
      const float dc = fmaxf(c2, 1e-5f);
      const float u = 2.0f * (c0 / dc) / 1599.0f - 1.0f;
      const float v = 2.0f * (c1 / dc) /  899.0f - 1.0f;
      const bool valid = (u >= -1.f) && (u <= 1.f) && (v >= -1.f) && (v <= 1.f)
                         && (c2 > 1e-5f);
      if (valid) {
        cnt[r] += 1.f;
        const float x = ((u + 1.f) * (float)WF - 1.f) * 0.5f;
        const float y = ((v + 1.f) * (float)HF - 1.f) * 0.5f;
        const float x0f = floorf(x), y0f = floorf(y);
        const int   x0 = (int)x0f,  y0 = (int)y0f;
        const float fx = x - x0f,   fy = y - y0f;
        const float w00 = (1.f-fx)*(1.f-fy);
        const float w10 = fx*(1.f-fy);
        const float w01 = (1.f-fx)*fy;
        const float w11 = fx*fy;
        const float* fb = imgf + ((size_t)((b*NCAM + n)*CN) + tid) * (HF*WF);
        const bool xb0 = (x0   >= 0) && (x0   < WF);
        const bool xb1 = (x0+1 >= 0) && (x0+1 < WF);
        const bool yb0 = (y0   >= 0) && (y0   < HF);
        const bool yb1 = (y0+1 >= 0) && (y0+1 < HF);
        const int i00 = y0*WF + x0;
        float sv = 0.f;
        if (xb0 && yb0) sv += w00 * fb[i00];
        if (xb1 && yb0) sv += w10 * fb[i00 + 1];
        if (xb0 && yb1) sv += w01 * fb[i00 + WF];
        if (xb1 && yb1) sv += w11 * fb[i00 + WF + 1];
        fc[r] += sv;
      }
    }
  }
  #pragma unroll
  for (int r = 0; r < R; ++r) fc[r] /= fmaxf(cnt[r], 1.f);

  // ---- lidar gathers ----
  float fl[R];
  #pragma unroll
  for (int r = 0; r < R; ++r) {
    const float x = rxx[r] * (float)XL - 0.5f;   // ((2r-1+1)*X-1)/2
    const float y = ryy[r] * (float)YL - 0.5f;
    const float z = rzz[r] * (float)ZL - 0.5f;
    const float x0f = floorf(x), y0f = floorf(y), z0f = floorf(z);
    const int x0 = (int)x0f, y0 = (int)y0f, z0 = (int)z0f;
    const float fx = x - x0f, fy = y - y0f, fz = z - z0f;
    const float wx[2] = {1.f-fx, fx}, wy[2] = {1.f-fy, fy}, wz[2] = {1.f-fz, fz};
    const bool xb[2] = { x0 >= 0 && x0 < XL, x0+1 >= 0 && x0+1 < XL };
    const bool yb[2] = { y0 >= 0 && y0 < YL, y0+1 >= 0 && y0+1 < YL };
    const bool zb[2] = { z0 >= 0 && z0 < ZL, z0+1 >= 0 && z0+1 < ZL };
    const float* lb = lidf + ((size_t)(b*CN) + tid) * (ZL*YL*XL);
    float sv = 0.f;
    #pragma unroll
    for (int dz = 0; dz < 2; ++dz)
      #pragma unroll
      for (int dy = 0; dy < 2; ++dy)
        #pragma unroll
        for (int dx = 0; dx < 2; ++dx)
          if (xb[dx] && yb[dy] && zb[dz]) {
            const int idx = (((z0+dz)*YL) + (y0+dy))*XL + (x0+dx);
            sv += wx[dx]*wy[dy]*wz[dz] * lb[idx];
          }
    fl[r] = sv;
  }

  // ---- stage features [ch][r] ----
  #pragma unroll
  for (int r = 0; r < R; ++r) { s_a[tid*R + r] = fc[r]; s_b[tid*R + r] = fl[r]; }
  __syncthreads();

  // ---- cam/lidar projections: 1 weight load feeds 8 FMAs ----
  float pc[R] = {0,0,0,0}, pl[R] = {0,0,0,0};
  #pragma unroll 4
  for (int k = 0; k < CN; ++k) {
    const float wc = cam_w[k*CN + tid];
    const float wl = lid_w[k*CN + tid];
    const float4 xc = *(const float4*)&s_a[k*R];
    const float4 xl = *(const float4*)&s_b[k*R];
    pc[0] += xc.x*wc; pc[1] += xc.y*wc; pc[2] += xc.z*wc; pc[3] += xc.w*wc;
    pl[0] += xl.x*wl; pl[1] += xl.y*wl; pl[2] += xl.z*wl; pl[3] += xl.w*wl;
  }
  const float pcb = cam_b[tid], plb = lid_b[tid];
  __syncthreads();               // done reading s_a/s_b
  #pragma unroll
  for (int r = 0; r < R; ++r) {
    s_a[tid*R + r] = s_w0[r] * (pc[r] + pcb);
    s_b[tid*R + r] = s_w1[r] * (pl[r] + plb);
  }
  __syncthreads();

  // ---- fusion layer 1 (512 -> 256) ----
  float t1[R] = {0,0,0,0};
  #pragma unroll 2
  for (int k = 0; k < CN; ++k) {
    const float wA = fus_w1[k*CN + tid];
    const float wB = fus_w1[(size_t)(CN + k)*CN + tid];
    const float4 xa = *(const float4*)&s_a[k*R];
    const float4 xb = *(const float4*)&s_b[k*R];
    t1[0] += xa.x*wA + xb.x*wB;
    t1[1] += xa.y*wA + xb.y*wB;
    t1[2] += xa.z*wA + xb.z*wB;
    t1[3] += xa.w*wA + xb.w*wB;
  }
  {
    const float bb = fus_b1[tid];
    #pragma unroll
    for (int r = 0; r < R; ++r) t1[r] += bb;
  }

  // ---- layer norm (two-pass) + relu ----
  #pragma unroll
  for (int r = 0; r < R; ++r) {
    float s1 = t1[r];
    #pragma unroll
    for (int o = 32; o > 0; o >>= 1) s1 += __shfl_down(s1, o);
    if (lane == 0) s_sum[r*4 + wv] = s1;
  }
  __syncthreads();
  float mu[R];
  #pragma unroll
  for (int r = 0; r < R; ++r)
    mu[r] = (s_sum[r*4+0] + s_sum[r*4+1] + s_sum[r*4+2] + s_sum[r*4+3]) * (1.f/256.f);
  #pragma unroll
  for (int r = 0; r < R; ++r) {
    const float d = t1[r] - mu[r];
    float s2 = d * d;
    #pragma unroll
    for (int o = 32; o > 0; o >>= 1) s2 += __shfl_down(s2, o);
    if (lane == 0) s_sq[r*4 + wv] = s2;
  }
  __syncthreads();
  {
    const float g = ln_g[tid], be = ln_b[tid];
    #pragma unroll
    for (int r = 0; r < R; ++r) {
      const float var = (s_sq[r*4+0] + s_sq[r*4+1] + s_sq[r*4+2] + s_sq[r*4+3]) * (1.f/256.f);
      const float ri = rsqrtf(var + 1e-5f);
      const float t2 = fmaxf((t1[r] - mu[r]) * ri * g + be, 0.f);
      s_t[tid*R + r] = t2;
    }
  }
  __syncthreads();

  // ---- output projection (256 -> 256) ----
  float o[R] = {0,0,0,0};
  #pragma unroll 4
  for (int k = 0; k < CN; ++k) {
    const float w = fus_w2[k*CN + tid];
    const float4 xt = *(const float4*)&s_t[k*R];
    o[0] += xt.x*w; o[1] += xt.y*w; o[2] += xt.z*w; o[3] += xt.w*w;
  }
  const float ob = fus_b2[tid];
  #pragma unroll
  for (int r = 0; r < R; ++r)
    out[(size_t)(q0+r)*CN + tid] = o[r] + ob;
}

extern "C" void kernel_launch(void* const* d_in, const int* in_sizes, int n_in,
                              void* d_out, int out_size, void* d_ws, size_t ws_size,
                              hipStream_t stream) {
  const float* query   = (const float*)d_in[0];
  const float* rpts    = (const float*)d_in[1];
  const float* imgf    = (const float*)d_in[2];
  const float* lidf    = (const float*)d_in[3];
  const float* l2i     = (const float*)d_in[4];
  const float* cam_w   = (const float*)d_in[5];
  const float* cam_b   = (const float*)d_in[6];
  const float* lid_w   = (const float*)d_in[7];
  const float* lid_b   = (const float*)d_in[8];
  const float* att_w1  = (const float*)d_in[9];
  const float* att_b1  = (const float*)d_in[10];
  const float* att_w2  = (const float*)d_in[11];
  const float* att_b2  = (const float*)d_in[12];
  const float* fus_w1  = (const float*)d_in[13];
  const float* fus_b1  = (const float*)d_in[14];
  const float* ln_g    = (const float*)d_in[15];
  const float* ln_b    = (const float*)d_in[16];
  const float* fus_w2  = (const float*)d_in[17];
  const float* fus_b2  = (const float*)d_in[18];
  float* out = (float*)d_out;

  dim3 grid((BN * QN) / R);
  dim3 block(256);
  mafs_fused<<<grid, block, 0, stream>>>(
      query, rpts, imgf, lidf, l2i,
      cam_w, cam_b, lid_w, lid_b,
      att_w1, att_b1, att_w2, att_b2,
      fus_w1, fus_b1, ln_g, ln_b, fus_w2, fus_b2, out);
}